// Round 1
// baseline (903.495 us; speedup 1.0000x reference)
//
#include <hip/hip_runtime.h>
#include <hip/hip_bf16.h>
#include <cstdint>
#include <cstddef>

// ---------------------------------------------------------------------------
// Types & helpers
// ---------------------------------------------------------------------------
typedef _Float16 f16x8_t __attribute__((ext_vector_type(8)));
typedef float    f32x4_t __attribute__((ext_vector_type(4)));
typedef unsigned short u16x8_t __attribute__((ext_vector_type(8)));
typedef unsigned short u16x4_t __attribute__((ext_vector_type(4)));

__device__ __forceinline__ unsigned short f2h(float f) {
    return __builtin_bit_cast(unsigned short, (_Float16)f);
}
__device__ __forceinline__ float h2f(unsigned short h) {
    return (float)__builtin_bit_cast(_Float16, h);
}
__device__ __forceinline__ f16x8_t load_h8(const unsigned short* p) {
    u16x8_t r = *(const u16x8_t*)p;
    return __builtin_bit_cast(f16x8_t, r);
}

// ---------------------------------------------------------------------------
// Problem constants
// ---------------------------------------------------------------------------
// x: [16, 512, 56, 56] f32 ; mid = 256 ; out: [16, 512, 56, 56] f32
#define BATCH 16
#define CFULL 512
#define CMID  256
#define HW    3136   // 56*56
#define WDIM  56

// ---------------------------------------------------------------------------
// prep_tabs: top-k ranks + sigmoid scales + BN (a,b) constants + zero pad
//   bnab layout: [4][2][256] floats: q=0 bn31, 1 bn33, 2 bna1, 3 bna2
// ---------------------------------------------------------------------------
__global__ void prep_tabs(const float* __restrict__ cscore,
                          const float* __restrict__ bn31, const float* __restrict__ bn33,
                          const float* __restrict__ bna1, const float* __restrict__ bna2,
                          int* __restrict__ pos_tab, float* __restrict__ scale_tab,
                          float* __restrict__ bnab, unsigned short* __restrict__ zpad)
{
    __shared__ float s[1024];
    int t = threadIdx.x;
    s[t] = cscore[t];
    __syncthreads();
    float sj = s[t];
    int cnt = 0;
    for (int k = 0; k < 1024; ++k) {
        float sk = s[k];
        cnt += (sk > sj) || (sk == sj && k < t);
    }
    pos_tab[t]   = (cnt < 512) ? cnt : -1;
    scale_tab[t] = 1.0f / (1.0f + expf(-sj));

    if (t < 256) {
        const float* srcs[4] = {bn31, bn33, bna1, bna2};
        #pragma unroll
        for (int q = 0; q < 4; ++q) {
            const float* sp = srcs[q];
            float g = sp[t], b = sp[256 + t], m = sp[512 + t], v = sp[768 + t];
            float a = g * rsqrtf(v + 1e-5f);
            bnab[q * 512 + t]       = a;
            bnab[q * 512 + 256 + t] = b - m * a;
        }
    }
    if (t < 512) zpad[t] = 0;
}

// ---------------------------------------------------------------------------
// prep_weights: build fp16 weights, fuse_weight folded in.
//   Wcat  [768][512]   rows 0..255 = w_1x1*fw1, 256..511 = w31*fw2, 512..767 = wa1*fw3
//   Wmain [256][9][512] = w_main[o][c][kh][kw]*fw0  (k order: tap-major, c-minor)
//   W33r  [256][9][256] = w33[o][c][kh][kw]
// ---------------------------------------------------------------------------
__global__ void prep_weights(const float* __restrict__ w_main, const float* __restrict__ w_1x1,
                             const float* __restrict__ w31, const float* __restrict__ wa1,
                             const float* __restrict__ w33, const float* __restrict__ fw,
                             unsigned short* __restrict__ Wcat,
                             unsigned short* __restrict__ Wmain,
                             unsigned short* __restrict__ W33r)
{
    int i = blockIdx.x * 256 + threadIdx.x;
    if (i < 393216) {                         // Wcat: 768*512
        int row = i >> 9, c = i & 511;
        float v;
        if (row < 256)      v = w_1x1[row * 512 + c] * fw[1];
        else if (row < 512) v = w31[(row - 256) * 512 + c] * fw[2];
        else                v = wa1[(row - 512) * 512 + c] * fw[3];
        Wcat[i] = f2h(v);
    } else if (i < 393216 + 1179648) {        // Wmain: 256*9*512
        int j = i - 393216;
        int o = j / 4608, r = j % 4608, tap = r >> 9, c = r & 511;
        Wmain[j] = f2h(w_main[(size_t)(o * 512 + c) * 9 + tap] * fw[0]);
    } else if (i < 2162688) {                 // W33r: 256*9*256
        int j = i - 1572864;
        int o = j / 2304, r = j % 2304, tap = r >> 8, c = r & 255;
        W33r[j] = f2h(w33[(size_t)(o * 256 + c) * 9 + tap]);
    }
}

// ---------------------------------------------------------------------------
// transpose_x: NCHW f32 -> NHWC f16.  grid (49, 8, 16), block 256.
// ---------------------------------------------------------------------------
__global__ void transpose_x(const float* __restrict__ x, unsigned short* __restrict__ xt)
{
    __shared__ unsigned short tile[64][65];
    int t = threadIdx.x;
    int hw0 = blockIdx.x * 64, c0 = blockIdx.y * 64, b = blockIdx.z;
    const float* xb = x + ((size_t)b * CFULL + c0) * HW + hw0;
    int hwL = t & 63, cL = t >> 6;
    #pragma unroll
    for (int i = 0; i < 16; ++i) {
        int c = cL + i * 4;
        tile[c][hwL] = f2h(xb[(size_t)c * HW + hwL]);
    }
    __syncthreads();
    int c8 = (t & 7) * 8, hw = t >> 3;
    #pragma unroll
    for (int i = 0; i < 2; ++i) {
        int hh = hw + i * 32;
        u16x8_t v;
        #pragma unroll
        for (int j = 0; j < 8; ++j) v[j] = tile[c8 + j][hh];
        *(u16x8_t*)(xt + ((size_t)b * HW + hw0 + hh) * CFULL + c0 + c8) = v;
    }
}

// ---------------------------------------------------------------------------
// conv_mfma: implicit-GEMM conv, NHWC fp16 input, direct-global fragments.
//   Block: 256 thr = 4 waves (2x2), wave tile 64ch x 112sp, block 128 x 224.
//   MODE 0 = main 3x3 (scatter, cbase 0)
//   MODE 1 = fused 1x1 x3 (seg0: scatter cbase 256; seg1: bn31->u; seg2: bna1->avgin)
//   MODE 2 = mid 3x3 (bn33 + scatter, cbase 512)
// ---------------------------------------------------------------------------
#define MODE_MAIN  0
#define MODE_FUSED 1
#define MODE_MID   2

template<int CIN, int NTAP, int MODE>
__global__ __launch_bounds__(256, 2)
void conv_mfma(const unsigned short* __restrict__ X,
               const unsigned short* __restrict__ Wr,
               const unsigned short* __restrict__ zpad,
               float* __restrict__ out,
               unsigned short* __restrict__ u_dst,
               unsigned short* __restrict__ avg_dst,
               const float* __restrict__ ab1,
               const float* __restrict__ ab2,
               const int* __restrict__ pos_tab,
               const float* __restrict__ scale_tab)
{
    const int lane = threadIdx.x & 63;
    const int wid  = threadIdx.x >> 6;
    const int wm = wid >> 1, wn = wid & 1;
    const int lr = lane & 15;
    const int ko = (lane >> 4) * 8;
    const int b  = blockIdx.z;
    const int ob = blockIdx.y;
    const int pb = blockIdx.x;
    const int o_wave = ob * 128 + wm * 64;
    const int p_wave = pb * 224 + wn * 112;

    int h_[7], w_[7], p_[7];
    #pragma unroll
    for (int n = 0; n < 7; ++n) {
        int p = p_wave + n * 16 + lr;
        p_[n] = p; h_[n] = p / WDIM; w_[n] = p % WDIM;
    }

    const unsigned short* xb = X + (size_t)b * HW * CIN;

    f32x4_t acc[4][7];
    #pragma unroll
    for (int m = 0; m < 4; ++m)
        #pragma unroll
        for (int n = 0; n < 7; ++n)
            acc[m][n] = (f32x4_t){0.f, 0.f, 0.f, 0.f};

    const unsigned short* ap[4];
    #pragma unroll
    for (int m = 0; m < 4; ++m)
        ap[m] = Wr + (size_t)(o_wave + m * 16 + lr) * (NTAP * CIN) + ko;

    for (int tap = 0; tap < NTAP; ++tap) {
        const int dh = (NTAP == 9) ? (tap / 3 - 1) : 0;
        const int dw = (NTAP == 9) ? (tap % 3 - 1) : 0;
        const unsigned short* bp[7];
        #pragma unroll
        for (int n = 0; n < 7; ++n) {
            int hh = h_[n] + dh, ww = w_[n] + dw;
            bool v = ((unsigned)hh < (unsigned)WDIM) && ((unsigned)ww < (unsigned)WDIM);
            bp[n] = v ? (xb + (size_t)(hh * WDIM + ww) * CIN + ko) : zpad;
        }
        #pragma unroll 4
        for (int kc = 0; kc < CIN / 32; ++kc) {
            f16x8_t af[4], bfr[7];
            #pragma unroll
            for (int m = 0; m < 4; ++m) af[m] = load_h8(ap[m] + kc * 32);
            #pragma unroll
            for (int n = 0; n < 7; ++n) bfr[n] = load_h8(bp[n] + kc * 32);
            #pragma unroll
            for (int m = 0; m < 4; ++m)
                #pragma unroll
                for (int n = 0; n < 7; ++n)
                    acc[m][n] = __builtin_amdgcn_mfma_f32_16x16x32_f16(af[m], bfr[n], acc[m][n], 0, 0, 0);
        }
        #pragma unroll
        for (int m = 0; m < 4; ++m) ap[m] += CIN;
    }

    // ---------------- epilogue ----------------
    const int fq = lane >> 4;
    const int seg = (MODE == MODE_FUSED) ? (ob >> 1) : 0;

    #pragma unroll
    for (int m = 0; m < 4; ++m) {
        const int orow = o_wave + m * 16 + fq * 4;
        #pragma unroll
        for (int n = 0; n < 7; ++n) {
            const int p = p_[n];
            f32x4_t v = acc[m][n];
            if (MODE == MODE_FUSED && seg != 0) {
                // BN + NHWC fp16 write (seg1 -> u via bn31, seg2 -> avgin via bna1)
                const int lc0 = orow - seg * 256;
                const float* ab = (seg == 1) ? ab1 : ab2;
                unsigned short* dst = (seg == 1) ? u_dst : avg_dst;
                u16x4_t pk;
                #pragma unroll
                for (int j = 0; j < 4; ++j) {
                    float a = ab[lc0 + j], bb = ab[256 + lc0 + j];
                    pk[j] = f2h(a * v[j] + bb);
                }
                *(u16x4_t*)(dst + ((size_t)b * HW + p) * CMID + lc0) = pk;
            } else {
                const int cbase = (MODE == MODE_MAIN) ? 0 : ((MODE == MODE_MID) ? 512 : 256);
                #pragma unroll
                for (int j = 0; j < 4; ++j) {
                    int o = orow + j;
                    float val = v[j];
                    if (MODE == MODE_MID) val = ab1[o] * val + ab1[256 + o];
                    int jc = cbase + o;
                    int pos = pos_tab[jc];
                    if (pos >= 0)
                        out[((size_t)b * CFULL + pos) * HW + p] = val * scale_tab[jc];
                }
            }
        }
    }
}

// ---------------------------------------------------------------------------
// avgpool 3x3 s1 p1 (count_include_pad) + bna2 + scatter. grid (392,16), blk 256.
// avgin is NHWC fp16 [B][3136][256].
// ---------------------------------------------------------------------------
__global__ void avgpool_bn(const unsigned short* __restrict__ avgin,
                           const float* __restrict__ ab2,
                           const int* __restrict__ pos_tab,
                           const float* __restrict__ scale_tab,
                           float* __restrict__ out)
{
    int t = threadIdx.x;
    int b = blockIdx.y;
    int p = blockIdx.x * 8 + (t >> 5);
    int c0 = (t & 31) * 8;
    int h = p / WDIM, w = p % WDIM;
    float s[8];
    #pragma unroll
    for (int j = 0; j < 8; ++j) s[j] = 0.f;
    #pragma unroll
    for (int dh = -1; dh <= 1; ++dh) {
        int hh = h + dh;
        if ((unsigned)hh >= (unsigned)WDIM) continue;
        #pragma unroll
        for (int dw = -1; dw <= 1; ++dw) {
            int ww = w + dw;
            if ((unsigned)ww >= (unsigned)WDIM) continue;
            u16x8_t v = *(const u16x8_t*)(avgin + ((size_t)b * HW + hh * WDIM + ww) * CMID + c0);
            #pragma unroll
            for (int j = 0; j < 8; ++j) s[j] += h2f(v[j]);
        }
    }
    #pragma unroll
    for (int j = 0; j < 8; ++j) {
        int c = c0 + j;
        int jc = 768 + c;
        int pos = pos_tab[jc];
        if (pos >= 0) {
            float val = (s[j] * (1.f / 9.f)) * ab2[c] + ab2[256 + c];
            out[((size_t)b * CFULL + pos) * HW + p] = val * scale_tab[jc];
        }
    }
}

// ---------------------------------------------------------------------------
// Launch
// ---------------------------------------------------------------------------
extern "C" void kernel_launch(void* const* d_in, const int* in_sizes, int n_in,
                              void* d_out, int out_size, void* d_ws, size_t ws_size,
                              hipStream_t stream) {
    (void)in_sizes; (void)n_in; (void)out_size; (void)ws_size;
    const float* x      = (const float*)d_in[0];
    const float* w_main = (const float*)d_in[1];
    const float* w_1x1  = (const float*)d_in[2];
    const float* w31    = (const float*)d_in[3];
    const float* bn31   = (const float*)d_in[4];
    const float* w33    = (const float*)d_in[5];
    const float* bn33   = (const float*)d_in[6];
    const float* wa1    = (const float*)d_in[7];
    const float* bna1   = (const float*)d_in[8];
    const float* bna2   = (const float*)d_in[9];
    const float* fw     = (const float*)d_in[10];
    const float* cscore = (const float*)d_in[11];
    float* out = (float*)d_out;

    char* ws = (char*)d_ws;
    unsigned short* x_nhwc = (unsigned short*)(ws);                 // 51,380,224 B
    unsigned short* u_nhwc = (unsigned short*)(ws + 51380224);      // 25,690,112 B
    unsigned short* avgin  = (unsigned short*)(ws + 77070336);      // 25,690,112 B
    unsigned short* Wcat   = (unsigned short*)(ws + 102760448);     //    786,432 B
    unsigned short* Wmain  = (unsigned short*)(ws + 103546880);     //  2,359,296 B
    unsigned short* W33r   = (unsigned short*)(ws + 105906176);     //  1,179,648 B
    float*          bnab   = (float*)        (ws + 107085824);      //      8,192 B
    int*            pos_tab= (int*)          (ws + 107094016);      //      4,096 B
    float*          scl_tab= (float*)        (ws + 107098112);      //      4,096 B
    unsigned short* zpad   = (unsigned short*)(ws + 107102208);     //      1,024 B

    dim3 blk(256);

    prep_tabs<<<dim3(1), dim3(1024), 0, stream>>>(cscore, bn31, bn33, bna1, bna2,
                                                  pos_tab, scl_tab, bnab, zpad);
    prep_weights<<<dim3(8448), blk, 0, stream>>>(w_main, w_1x1, w31, wa1, w33, fw,
                                                 Wcat, Wmain, W33r);
    transpose_x<<<dim3(49, 8, 16), blk, 0, stream>>>(x, x_nhwc);

    // fused 1x1 GEMM: 768 out channels (1x1-branch / w31->u / wa1->avgin)
    conv_mfma<512, 1, MODE_FUSED><<<dim3(14, 6, 16), blk, 0, stream>>>(
        x_nhwc, Wcat, zpad, out, u_nhwc, avgin,
        bnab + 0 * 512, bnab + 2 * 512, pos_tab, scl_tab);

    // main 3x3 conv
    conv_mfma<512, 9, MODE_MAIN><<<dim3(14, 2, 16), blk, 0, stream>>>(
        x_nhwc, Wmain, zpad, out, nullptr, nullptr,
        nullptr, nullptr, pos_tab, scl_tab);

    // mid 3x3 conv (input u, bn33 epilogue)
    conv_mfma<256, 9, MODE_MID><<<dim3(14, 2, 16), blk, 0, stream>>>(
        u_nhwc, W33r, zpad, out, nullptr, nullptr,
        bnab + 1 * 512, nullptr, pos_tab, scl_tab);

    // avgpool + bna2
    avgpool_bn<<<dim3(392, 16), blk, 0, stream>>>(avgin, bnab + 3 * 512,
                                                  pos_tab, scl_tab, out);
}